// Round 8
// baseline (136.708 us; speedup 1.0000x reference)
//
#include <hip/hip_runtime.h>
#include <hip/hip_bf16.h>

// HardAttention = GEMM out=tanh([ctx|outp]@W^T+b) (M=16384,K=1024,N=512, bf16 MFMA)
//               + attn = constant one-hot [4,4096,4096] (256 MiB write stream).
// Round-7 (79us) proved barrier-free wave-autonomous tiles. Round 8: LDS-FREE.
// Key fact: mfma_16x16x32 A-frag for lane l is A[row=l&15][k=(l>>4)*8..+8] -- 8 CONSECUTIVE
// floats in row-major A (and likewise W) -> fragments load directly from global (16x128B
// segments/wave), no cross-lane redistribution, no LDS, no lgkm wait. Explicit 2-deep
// register double-buffer (named bufs, static indices); native __float2bfloat16 casts
// (compiler-fused cvt path, m240) replace 4-op manual RNE. XCD-chunked block swizzle.

typedef __attribute__((ext_vector_type(8))) short bf16x8;   // 8 bf16 = 4 VGPRs
typedef __attribute__((ext_vector_type(4))) float f32x4;

#define B_N 4
#define L_N 4096
#define S_N 4096
#define D_N 512
#define M_N (B_N * L_N)   // 16384
#define K_N (2 * D_N)     // 1024

#define NTHREADS 256      // 4 waves/block
#define NBLOCKS 512       // 2048 waves = 256 mtiles x 8 ntiles
#define NSTEPS 32         // K / 32

static __device__ __forceinline__ short f2bf(float f) {
  return __builtin_bit_cast(short, __float2bfloat16(f));   // RNE; compiler-preferred path
}

static __device__ __forceinline__ bf16x8 pack8(f32x4 a, f32x4 b) {
  bf16x8 r;
  r[0] = f2bf(a.x); r[1] = f2bf(a.y); r[2] = f2bf(a.z); r[3] = f2bf(a.w);
  r[4] = f2bf(b.x); r[5] = f2bf(b.y); r[6] = f2bf(b.z); r[7] = f2bf(b.w);
  return r;
}

__global__ __launch_bounds__(NTHREADS, 2)
void gemm_fill(const float* __restrict__ outp, const float* __restrict__ ctx,
               const float* __restrict__ Wm, const float* __restrict__ bias,
               float* __restrict__ dout)
{
  const int tid  = threadIdx.x;
  const int lane = tid & 63;
  const int wid  = tid >> 6;
  // XCD-chunked swizzle (bijective: 512 = 8*64): XCD x handles logical blocks x*64..x*64+63,
  // i.e. mtiles x*32..x*32+31 -> each A panel + its pair stay in one XCD's L2.
  const int sb = (blockIdx.x & 7) * 64 + (blockIdx.x >> 3);
  const int gwave = sb * 4 + wid;
  const int mtile = gwave >> 3;       // 256 tiles of 64 rows
  const int ntile = gwave & 7;        // 8 tiles of 64 cols
  const int m0 = mtile * 64;
  const int n0 = ntile * 64;

  const int l15 = lane & 15;
  const int lq  = lane >> 4;          // k-slot: this lane's 8-float k-slice

  // per-lane fragment offsets (elements): frag i row = tile0 + i*16 + l15, k base = lq*8
  int aoff[4], woff[4];
#pragma unroll
  for (int i = 0; i < 4; ++i) {
    aoff[i] = (m0 + i * 16 + l15) * D_N + lq * 8;
    woff[i] = (n0 + i * 16 + l15) * K_N + lq * 8;
  }

  // fill: this wave covers f32x4 indices [gwave*8192, (gwave+1)*8192)
  f32x4* attn4 = (f32x4*)(dout + (size_t)M_N * D_N) + (size_t)gwave * (NSTEPS * 256);

  f32x4 acc[4][4] = {};
  f32x4 pAa[8], pAw[8], pBa[8], pBw[8];   // two named prefetch buffers (static idx, rule #20)

#define LOADF(fa, fw, T)                                                        \
  {                                                                             \
    const int tn_ = (T);                                                        \
    const float* ab_ = (tn_ < 16 ? ctx : outp);                                 \
    const int ka_ = (tn_ & 15) * 32;                                            \
    const int kw_ = tn_ * 32;                                                   \
    _Pragma("unroll")                                                           \
    for (int i = 0; i < 4; ++i) {                                               \
      fa[2 * i]     = *(const f32x4*)(ab_ + aoff[i] + ka_);                     \
      fa[2 * i + 1] = *(const f32x4*)(ab_ + aoff[i] + ka_ + 4);                 \
      fw[2 * i]     = *(const f32x4*)(Wm  + woff[i] + kw_);                     \
      fw[2 * i + 1] = *(const f32x4*)(Wm  + woff[i] + kw_ + 4);                 \
    }                                                                           \
  }

#define STEPC(fa, fw, T)                                                        \
  {                                                                             \
    const int t_ = (T);                                                         \
    bf16x8 af_[4], wf_[4];                                                      \
    _Pragma("unroll")                                                           \
    for (int i = 0; i < 4; ++i) {                                               \
      af_[i] = pack8(fa[2 * i], fa[2 * i + 1]);                                 \
      wf_[i] = pack8(fw[2 * i], fw[2 * i + 1]);                                 \
    }                                                                           \
    _Pragma("unroll")                                                           \
    for (int s = 0; s < 4; ++s) {                                               \
      const int li = t_ * 256 + (s << 6) + lane;        /* local f32x4 idx   */ \
      const int gi = gwave * (NSTEPS * 256) + li;                               \
      const int col4 = (gi & 1023) << 2;                                        \
      const int l_   = (gi >> 10) & 4095;                                       \
      f32x4 v;                                                                  \
      v.x = (col4     == l_) ? 1.0f : 0.0f;                                     \
      v.y = (col4 + 1 == l_) ? 1.0f : 0.0f;                                     \
      v.z = (col4 + 2 == l_) ? 1.0f : 0.0f;                                     \
      v.w = (col4 + 3 == l_) ? 1.0f : 0.0f;                                     \
      __builtin_nontemporal_store(v, attn4 + li);                               \
    }                                                                           \
    _Pragma("unroll")                                                           \
    for (int i = 0; i < 4; ++i)                                                 \
      _Pragma("unroll")                                                         \
      for (int j = 0; j < 4; ++j)                                               \
        acc[i][j] = __builtin_amdgcn_mfma_f32_16x16x32_bf16(af_[i], wf_[j],     \
                                                            acc[i][j], 0, 0, 0);\
  }

  // prologue: step 0 -> buffer A
  LOADF(pAa, pAw, 0)

#pragma unroll 1
  for (int tt = 0; tt < NSTEPS; tt += 2) {
    LOADF(pBa, pBw, tt + 1)          // prefetch t+1 while computing t
    STEPC(pAa, pAw, tt)
    if (tt + 2 < NSTEPS) LOADF(pAa, pAw, tt + 2)
    STEPC(pBa, pBw, tt + 1)
  }

#undef LOADF
#undef STEPC

  // epilogue: C/D layout col=lane&15, row=(lane>>4)*4+reg (verified R1/m89/m91)
  const int r0  = m0 + (lq << 2);
  const int c0g = n0 + l15;
  float bv[4];
#pragma unroll
  for (int j = 0; j < 4; ++j) bv[j] = bias[c0g + j * 16];
#pragma unroll
  for (int i = 0; i < 4; ++i)
#pragma unroll
    for (int j = 0; j < 4; ++j)
#pragma unroll
      for (int r = 0; r < 4; ++r) {
        const int m = r0 + i * 16 + r;
        const int n = c0g + j * 16;
        dout[(size_t)m * D_N + n] = tanhf(acc[i][j][r] + bv[j]);
      }
}

extern "C" void kernel_launch(void* const* d_in, const int* in_sizes, int n_in,
                              void* d_out, int out_size, void* d_ws, size_t ws_size,
                              hipStream_t stream) {
  const float* outp = (const float*)d_in[0];
  const float* ctx  = (const float*)d_in[1];
  const float* Wm   = (const float*)d_in[2];
  const float* bias = (const float*)d_in[3];
  float* dout = (float*)d_out;
  hipLaunchKernelGGL(gemm_fill, dim3(NBLOCKS), dim3(NTHREADS), 0, stream,
                     outp, ctx, Wm, bias, dout);
}

// Round 9
// 74.438 us; speedup vs baseline: 1.8365x; 1.8365x over previous
//
#include <hip/hip_runtime.h>
#include <hip/hip_bf16.h>

// HardAttention = GEMM out=tanh([ctx|outp]@W^T+b) (M=16384,K=1024,N=512, bf16 MFMA)
//               + attn = constant one-hot [4,4096,4096] (256 MiB write stream).
// Round-7 (79us): barrier-free wave-autonomous tiles, per-wave LDS staging. PROVEN.
// Round-8 lesson: LDS-free reg-double-buffer needs 128 VGPRs of buffers -> compiler sinks
// loads to uses (VGPR=116), pipeline gone, 137us. LDS staging IS the low-pressure prefetch.
// Round 9 = R7 byte-identical EXCEPT: manual 4-op RNE bf16 conversion replaced by native
// __float2bfloat16 (compiler fuses pairs to v_cvt_pk_bf16_f32, m240) -- removes ~13us of
// per-step VALU conversion from the critical path.

typedef __attribute__((ext_vector_type(8))) short bf16x8;   // 8 bf16 = 4 VGPRs
typedef __attribute__((ext_vector_type(4))) float f32x4;

#define B_N 4
#define L_N 4096
#define S_N 4096
#define D_N 512
#define M_N (B_N * L_N)   // 16384
#define K_N (2 * D_N)     // 1024

#define NTHREADS 256      // 4 waves/block
#define NBLOCKS 512       // 2048 waves total
#define NSTEPS 32         // K / 32

static __device__ __forceinline__ short f2bf(float f) {
  return __builtin_bit_cast(short, __float2bfloat16(f));   // RNE; fuses to v_cvt_pk_bf16_f32
}

static __device__ __forceinline__ bf16x8 pack8(f32x4 a, f32x4 b) {
  bf16x8 r;
  r[0] = f2bf(a.x); r[1] = f2bf(a.y); r[2] = f2bf(a.z); r[3] = f2bf(a.w);
  r[4] = f2bf(b.x); r[5] = f2bf(b.y); r[6] = f2bf(b.z); r[7] = f2bf(b.w);
  return r;
}

__global__ __launch_bounds__(NTHREADS, 2)
void gemm_fill(const float* __restrict__ outp, const float* __restrict__ ctx,
               const float* __restrict__ Wm, const float* __restrict__ bias,
               float* __restrict__ dout)
{
  // per-wave private LDS: A-scratch 4KB + W-scratch 4KB (64 rows x 32k bf16 each)
  __shared__ char lds[4][8192];

  const int tid  = threadIdx.x;
  const int lane = tid & 63;
  const int wid  = tid >> 6;
  const int gwave = blockIdx.x * 4 + wid;
  const int mtile = gwave >> 3;       // 256 tiles of 64 rows
  const int ntile = gwave & 7;        // 8 tiles of 64 cols
  const int m0 = mtile * 64;
  const int n0 = ntile * 64;

  char* As = lds[wid];
  char* Ws = lds[wid] + 4096;

  // staging: load q (0..3): local row lr = 16q + lrq, k-chunk ch (8 floats)
  const int lrq = lane >> 2;          // 0..15
  const int ch  = lane & 3;           // 0..3
  // LDS row = 64B (32 bf16). Swizzle: slot ^= ((row>>1)&3)<<4  -> exact 2-way banking
  // (free, m136) on both the write sweep (64 lanes = rows 0..15 x 4 chunks) and the
  // frag read (16 rows x 4 k-groups).
  const int wrB  = lrq * 64 + ((ch << 4) ^ (((lrq >> 1) & 3) << 4));       // + q*1024
  const int rdB  = (lane & 15) * 64 +
                   ((((lane >> 4) << 4)) ^ ((((lane & 15) >> 1) & 3) << 4)); // + i*1024

  // global staging bases (per-lane): A row m0+16q+lrq, W col n0+16q+lrq
  const float* aC = ctx  + (size_t)(m0 + lrq) * D_N + ch * 8;   // k-steps 0..15
  const float* aO = outp + (size_t)(m0 + lrq) * D_N + ch * 8;   // k-steps 16..31
  const float* wB = Wm   + (size_t)(n0 + lrq) * K_N + ch * 8;   // full k

  // fill: this wave covers f32x4 indices [gwave*8192, (gwave+1)*8192)
  f32x4* attn4 = (f32x4*)(dout + (size_t)M_N * D_N) + (size_t)gwave * (NSTEPS * 256);

  f32x4 acc[4][4] = {};
  f32x4 sa[8], sw[8];

  // ---- prologue: issue loads for step 0 ----
#pragma unroll
  for (int q = 0; q < 4; ++q) {
    sa[2*q]   = *(const f32x4*)(aC + q * (16 * D_N));
    sa[2*q+1] = *(const f32x4*)(aC + q * (16 * D_N) + 4);
    sw[2*q]   = *(const f32x4*)(wB + q * (16 * K_N));
    sw[2*q+1] = *(const f32x4*)(wB + q * (16 * K_N) + 4);
  }

#pragma unroll 1
  for (int t = 0; t < NSTEPS; ++t) {
    // ---- pack + ds_write staged data of step t (compiler waits the loads via
    //      counted vmcnt; previously-issued fill stores keep flying) ----
#pragma unroll
    for (int q = 0; q < 4; ++q) {
      *(bf16x8*)(As + q * 1024 + wrB) = pack8(sa[2*q], sa[2*q+1]);
      *(bf16x8*)(Ws + q * 1024 + wrB) = pack8(sw[2*q], sw[2*q+1]);
    }

    // ---- issue step t+1 loads (staging regs are free again) ----
    if (t + 1 < NSTEPS) {
      const int tn = t + 1;
      const float* ab = (tn < 16 ? aC : aO) + (tn & 15) * 32;
      const float* wb = wB + tn * 32;
#pragma unroll
      for (int q = 0; q < 4; ++q) {
        sa[2*q]   = *(const f32x4*)(ab + q * (16 * D_N));
        sa[2*q+1] = *(const f32x4*)(ab + q * (16 * D_N) + 4);
        sw[2*q]   = *(const f32x4*)(wb + q * (16 * K_N));
        sw[2*q+1] = *(const f32x4*)(wb + q * (16 * K_N) + 4);
      }
    }

    // ---- fill slice for step t: 4 NT float4 stores/lane, never force-drained ----
#pragma unroll
    for (int s = 0; s < 4; ++s) {
      const int gi = gwave * (NSTEPS * 256) + t * 256 + (s << 6) + lane; // f32x4 idx
      const int col4 = (gi & 1023) << 2;          // (gi*4) & 4095
      const int l    = (gi >> 10) & 4095;         // ((gi*4) >> 12) & 4095
      f32x4 v;
      v.x = (col4     == l) ? 1.0f : 0.0f;
      v.y = (col4 + 1 == l) ? 1.0f : 0.0f;
      v.z = (col4 + 2 == l) ? 1.0f : 0.0f;
      v.w = (col4 + 3 == l) ? 1.0f : 0.0f;
      __builtin_nontemporal_store(v, attn4 + (t * 256 + (s << 6) + lane));
    }

    // ---- fragments (lgkmcnt-counted, same wave) + 16 MFMA ----
    bf16x8 af[4], wf[4];
#pragma unroll
    for (int i = 0; i < 4; ++i) {
      af[i] = *(const bf16x8*)(As + i * 1024 + rdB);
      wf[i] = *(const bf16x8*)(Ws + i * 1024 + rdB);
    }
#pragma unroll
    for (int i = 0; i < 4; ++i)
#pragma unroll
      for (int j = 0; j < 4; ++j)
        acc[i][j] = __builtin_amdgcn_mfma_f32_16x16x32_bf16(af[i], wf[j], acc[i][j], 0, 0, 0);
  }

  // ---- epilogue: C/D layout col=lane&15, row=(lane>>4)*4+reg (verified R1/m89/m91) ----
  const int r0  = m0 + ((lane >> 4) << 2);
  const int c0g = n0 + (lane & 15);
  float bv[4];
#pragma unroll
  for (int j = 0; j < 4; ++j) bv[j] = bias[c0g + j * 16];
#pragma unroll
  for (int i = 0; i < 4; ++i)
#pragma unroll
    for (int j = 0; j < 4; ++j)
#pragma unroll
      for (int r = 0; r < 4; ++r) {
        const int m = r0 + i * 16 + r;
        const int n = c0g + j * 16;
        dout[(size_t)m * D_N + n] = tanhf(acc[i][j][r] + bv[j]);
      }
}

extern "C" void kernel_launch(void* const* d_in, const int* in_sizes, int n_in,
                              void* d_out, int out_size, void* d_ws, size_t ws_size,
                              hipStream_t stream) {
  const float* outp = (const float*)d_in[0];
  const float* ctx  = (const float*)d_in[1];
  const float* Wm   = (const float*)d_in[2];
  const float* bias = (const float*)d_in[3];
  float* dout = (float*)d_out;
  hipLaunchKernelGGL(gemm_fill, dim3(NBLOCKS), dim3(NTHREADS), 0, stream,
                     outp, ctx, Wm, bias, dout);
}